// Round 6
// baseline (532.814 us; speedup 1.0000x reference)
//
#include <hip/hip_runtime.h>
#include <cstdio>
#include <cstdint>

// RGCN block, aggregation-first (round-5 + pipelined GEMM with counted vmcnt):
//   M[dst, r*256+ch] = mean_{edges (src->dst, rel=r)} x_bf16[src, ch]
//   A = [M | x_bf16]  (50048 x 2304),  B = [W_0..W_7 ; root]  (2304 x 256)
//   h = A @ B + bias  -> BN(batch stats) -> PReLU -> + x
// CSR grouped by (dst, rel) via counting sort; edge records are u16 src.
// GEMM: A-only LDS double-buffer, B read direct from L2-hot wbfT, raw s_barrier +
// s_waitcnt vmcnt(4) so next-tile global_load_lds stays in flight across barriers.
// NOTE: harness delivers integer inputs as int32 (edge_index int64 -> const int*).

constexpr int kN  = 50000;   // nodes
constexpr int kE  = 800000;  // edges
constexpr int kR  = 8;       // relations
constexpr int kC  = 256;     // channels
constexpr int kMP = 50048;   // padded rows (391*128)
constexpr int kK  = 2304;    // GEMM K = 8*256 + 256

typedef __attribute__((ext_vector_type(8))) short bf16x8;
typedef __attribute__((ext_vector_type(4))) float f32x4;
typedef __attribute__((ext_vector_type(2))) unsigned int u32x2;

__device__ __forceinline__ unsigned short f2bf(float f) {
  unsigned u = __builtin_bit_cast(unsigned, f);
  u = u + 0x7FFFu + ((u >> 16) & 1u);
  return (unsigned short)(u >> 16);
}
__device__ __forceinline__ float bf2f(unsigned short s) {
  unsigned u = ((unsigned)s) << 16;
  return __builtin_bit_cast(float, u);
}
__device__ __forceinline__ void gload16(const void* g, void* l) {
  __builtin_amdgcn_global_load_lds((__attribute__((address_space(1))) const void*)g,
                                   (__attribute__((address_space(3))) void*)l, 16, 0, 0);
}

// ---- per-edge counts: cnt[rel*N+dst], deg[dst] ----
__global__ void k_count(const int* __restrict__ ei, const float* __restrict__ ea,
                        int* __restrict__ cnt, int* __restrict__ deg) {
  int e = blockIdx.x * blockDim.x + threadIdx.x;
  if (e >= kE) return;
  int dst = ei[kE + e];
  int rel = (int)ea[(size_t)e * 5 + 4];
  if ((unsigned)dst >= (unsigned)kN || (unsigned)rel >= (unsigned)kR) return;
  atomicAdd(&cnt[rel * kN + dst], 1);
  atomicAdd(&deg[dst], 1);
}

// ---- convert x -> bf16 into A cols 2048..2303 ----
__global__ void k_convert_x(const float* __restrict__ x, unsigned short* __restrict__ A) {
  int i = (blockIdx.x * blockDim.x + threadIdx.x) * 4;
  if (i >= kN * kC) return;
  int row = i >> 8, col = i & 255;
  float4 v = *(const float4*)(x + i);
  ushort4 o;
  o.x = f2bf(v.x); o.y = f2bf(v.y); o.z = f2bf(v.z); o.w = f2bf(v.w);
  *(ushort4*)(A + (size_t)row * kK + 2048 + col) = o;
}

// ---- convert W+root -> bf16 transposed: wbfT[c][k], k<2048: W[k>>8][k&255][c]; else root[k-2048][c] ----
__global__ void k_convert_w(const float* __restrict__ W, const float* __restrict__ root,
                            unsigned short* __restrict__ wbfT) {
  int t = blockIdx.x * blockDim.x + threadIdx.x;   // c*kK + k
  if (t >= kC * kK) return;
  int c = t / kK, k = t - c * kK;
  float v;
  if (k < kR * kC) {
    int r = k >> 8, kk = k & 255;
    v = W[(size_t)r * kC * kC + (size_t)kk * kC + c];
  } else {
    v = root[(size_t)(k - kR * kC) * kC + c];
  }
  wbfT[(size_t)c * kK + k] = f2bf(v);
}

// ---- exclusive scan of deg -> off ----
__global__ __launch_bounds__(1024) void k_scan(const int* __restrict__ deg, int* __restrict__ off) {
  __shared__ int wsum[16];
  int t = threadIdx.x;
  const int slab = (kN + 1023) / 1024;   // 49
  int lo = t * slab, hi = min(lo + slab, kN);
  int s = 0;
  for (int i = lo; i < hi; ++i) s += deg[i];
  int incl = s;
#pragma unroll
  for (int d = 1; d < 64; d <<= 1) {
    int v = __shfl_up(incl, d);
    if ((t & 63) >= d) incl += v;
  }
  if ((t & 63) == 63) wsum[t >> 6] = incl;
  __syncthreads();
  if (t == 0) {
    int run = 0;
#pragma unroll
    for (int i = 0; i < 16; ++i) { int tmp = wsum[i]; wsum[i] = run; run += tmp; }
  }
  __syncthreads();
  int base = wsum[t >> 6] + incl - s;
  for (int i = lo; i < hi; ++i) { off[i] = base; base += deg[i]; }
  if (t == 1023) off[kN] = base;
}

// ---- per-(rel,dst) group cursors ----
__global__ void k_grp(const int* __restrict__ off, const int* __restrict__ cnt,
                      int* __restrict__ cur) {
  int t = blockIdx.x * blockDim.x + threadIdx.x;
  if (t >= kN) return;
  int o = off[t];
#pragma unroll
  for (int r = 0; r < kR; ++r) { cur[r * kN + t] = o; o += cnt[r * kN + t]; }
}

// ---- fill CSR edge records (u16 src), grouped (dst, rel) ----
__global__ void k_fill(const int* __restrict__ ei, const float* __restrict__ ea,
                       int* __restrict__ cur, unsigned short* __restrict__ ebuf) {
  int e = blockIdx.x * blockDim.x + threadIdx.x;
  if (e >= kE) return;
  int src = ei[e];
  int dst = ei[kE + e];
  int rel = (int)ea[(size_t)e * 5 + 4];
  if ((unsigned)dst >= (unsigned)kN || (unsigned)rel >= (unsigned)kR) return;
  int pos = atomicAdd(&cur[rel * kN + dst], 1);
  ebuf[pos] = (unsigned short)src;
}

// ---- aggregation: 1 wave per dst; mean x[src] per relation -> A cols 0..2047 (nontemporal) ----
__global__ __launch_bounds__(256) void k_agg(const unsigned short* __restrict__ ebuf,
                                             const int* __restrict__ off,
                                             const int* __restrict__ cnt,
                                             unsigned short* A) {
  int dst = blockIdx.x * 4 + (threadIdx.x >> 6);
  if (dst >= kN) return;
  int lane = threadIdx.x & 63;
  int e = off[dst];
  const unsigned short* xcols = A + 2048 + lane * 4;   // x region of A
  unsigned short* mrow = A + (size_t)dst * kK + lane * 4;
#pragma unroll
  for (int r = 0; r < kR; ++r) {
    int c = cnt[r * kN + dst];
    float s0 = 0.f, s1 = 0.f, s2 = 0.f, s3 = 0.f;
    for (int k = 0; k < c; ++k) {
      int src = ebuf[e + k];
      ushort4 v = *(const ushort4*)(xcols + (size_t)src * kK);
      s0 += bf2f(v.x); s1 += bf2f(v.y); s2 += bf2f(v.z); s3 += bf2f(v.w);
    }
    e += c;
    float sc = c > 0 ? 1.f / (float)c : 0.f;
    unsigned lo = (unsigned)f2bf(s0 * sc) | ((unsigned)f2bf(s1 * sc) << 16);
    unsigned hi = (unsigned)f2bf(s2 * sc) | ((unsigned)f2bf(s3 * sc) << 16);
    u32x2 pk = {lo, hi};
    __builtin_nontemporal_store(pk, (u32x2*)(mrow + r * 256));   // don't evict x from L3
  }
}

// ---- GEMM [kMP x 2304] @ [2304 x 256] -> d_out f32 (+bias), fused BN column stats ----
// A-only LDS double-buffer (2 x 16 KB), XOR-swizzled content; B fragments read direct
// from L2-resident wbfT. Counted vmcnt(4) keeps next-tile global_load_lds in flight
// across raw s_barriers (T3/T4: never drain vmcnt to 0 in the main loop).
__global__ __launch_bounds__(256) void k_gemm(const unsigned short* __restrict__ A,
                                              const unsigned short* __restrict__ wbfT,
                                              float* __restrict__ out,
                                              const float* __restrict__ bias,
                                              float* __restrict__ cs,
                                              float* __restrict__ csq) {
  __shared__ __align__(16) unsigned short As[2][128 * 64];  // dbuf, swizzled content
  const int tid = threadIdx.x;
  const int lane = tid & 63, wv = tid >> 6;
  const int n0 = blockIdx.x * 128, m0 = blockIdx.y * 128;
  const int wm = wv >> 1, wn = wv & 1;  // 2x2 wave grid, 64x64 out each
  f32x4 acc[4][4] = {};

  const int srow = (lane >> 3);                         // 0..7 == row&7
  const int skk  = ((lane & 7) ^ srow) * 8;             // pre-swizzled global k-chunk

#define STAGE(buf, kt)                                                            \
  {                                                                               \
    const int kb_ = (kt) * 64;                                                    \
    _Pragma("unroll")                                                             \
    for (int c = 0; c < 4; ++c) {                                                 \
      int row_ = c * 32 + wv * 8 + srow;                                          \
      gload16(A + (size_t)(m0 + row_) * kK + kb_ + skk,                           \
              &As[buf][c * 2048 + wv * 512]);                                     \
    }                                                                             \
  }

  STAGE(0, 0);
  constexpr int NT = kK / 64;  // 36
  for (int t = 0; t < NT; ++t) {
    const int buf = t & 1;
    if (t + 1 < NT) {
      STAGE(buf ^ 1, t + 1);
      asm volatile("s_waitcnt vmcnt(4)" ::: "memory");   // own 4 t-loads retired; t+1 in flight
    } else {
      asm volatile("s_waitcnt vmcnt(0)" ::: "memory");
    }
    __builtin_amdgcn_s_barrier();
    __builtin_amdgcn_sched_barrier(0);
    const int kb = t * 64;
#pragma unroll
    for (int kk = 0; kk < 64; kk += 32) {
      const int koff = kk + (lane >> 4) * 8;
      bf16x8 a[4], b[4];
#pragma unroll
      for (int j = 0; j < 4; ++j) {
        int col = n0 + wn * 64 + j * 16 + (lane & 15);
        b[j] = *(const bf16x8*)(wbfT + (size_t)col * kK + kb + koff);   // L2-hot
      }
#pragma unroll
      for (int i = 0; i < 4; ++i) {
        int ra = wm * 64 + i * 16 + (lane & 15);
        unsigned ba = (unsigned)(koff * 2) ^ (unsigned)((ra & 7) << 4);
        a[i] = *(const bf16x8*)((const char*)As[buf] + ra * 128 + ba);
      }
#pragma unroll
      for (int i = 0; i < 4; ++i)
#pragma unroll
        for (int j = 0; j < 4; ++j)
          acc[i][j] = __builtin_amdgcn_mfma_f32_16x16x32_bf16(a[i], b[j], acc[i][j], 0, 0, 0);
    }
    __builtin_amdgcn_s_barrier();            // protect As[buf^1... overwrite next iter
    __builtin_amdgcn_sched_barrier(0);
  }
#undef STAGE

  // C/D layout: col = lane&15, row = (lane>>4)*4 + r.  Stats on raw acc (bias-free;
  // pad rows have zero acc so they contribute nothing to the sums).
#pragma unroll
  for (int j = 0; j < 4; ++j) {
    int col = n0 + wn * 64 + j * 16 + (lane & 15);
    float bv = bias[col];
    float s = 0.f, ss = 0.f;
#pragma unroll
    for (int i = 0; i < 4; ++i) {
      int rb = m0 + wm * 64 + i * 16 + (lane >> 4) * 4;
#pragma unroll
      for (int q = 0; q < 4; ++q) {
        float v = acc[i][j][q];
        s += v; ss += v * v;
        int row = rb + q;
        if (row < kN) out[(size_t)row * kC + col] = v + bv;
      }
    }
    s  += __shfl_xor(s, 16);  s  += __shfl_xor(s, 32);
    ss += __shfl_xor(ss, 16); ss += __shfl_xor(ss, 32);
    if (lane < 16) { atomicAdd(&cs[col], s); atomicAdd(&csq[col], ss); }
  }
}

// ---- BN normalize + PReLU + residual (stats are bias-free; shift mu by bias) ----
__global__ void k_final(float* __restrict__ h, const float* __restrict__ x,
                        const float* __restrict__ cs, const float* __restrict__ csq,
                        const float* __restrict__ bias,
                        const float* __restrict__ gamma, const float* __restrict__ beta,
                        const float* __restrict__ prelu) {
  int idx = (blockIdx.x * blockDim.x + threadIdx.x) * 4;
  if (idx >= kN * kC) return;
  int col = idx & 255;
  const float inv_n = 1.0f / (float)kN;
  float a = prelu[0];
  float4 hv = *(float4*)(h + idx);
  float4 xv = *(const float4*)(x + idx);
  float hr[4] = {hv.x, hv.y, hv.z, hv.w};
  float xr[4] = {xv.x, xv.y, xv.z, xv.w};
#pragma unroll
  for (int j = 0; j < 4; ++j) {
    int c = col + j;
    float mu_raw = cs[c] * inv_n;
    float var = csq[c] * inv_n - mu_raw * mu_raw;
    float mu  = mu_raw + bias[c];          // h was stored with bias added
    float k   = gamma[c] * rsqrtf(var + 1e-5f);
    float v   = (hr[j] - mu) * k + beta[c];
    v = v > 0.f ? v : a * v;
    hr[j] = v + xr[j];
  }
  *(float4*)(h + idx) = make_float4(hr[0], hr[1], hr[2], hr[3]);
}

extern "C" void kernel_launch(void* const* d_in, const int* in_sizes, int n_in,
                              void* d_out, int out_size, void* d_ws, size_t ws_size,
                              hipStream_t stream) {
  const float* x     = (const float*)d_in[0];
  const int*   ei    = (const int*)d_in[1];     // int64 in ref -> int32 from harness
  const float* ea    = (const float*)d_in[2];
  const float* W     = (const float*)d_in[3];
  const float* root  = (const float*)d_in[4];
  const float* bias  = (const float*)d_in[5];
  const float* gamma = (const float*)d_in[6];
  const float* beta  = (const float*)d_in[7];
  const float* prelu = (const float*)d_in[8];
  float* out = (float*)d_out;
  char* ws = (char*)d_ws;

  size_t o = 0;
  auto alloc = [&](size_t sz) { size_t r = o; o += (sz + 255) & ~(size_t)255; return r; };
  size_t a_o   = alloc((size_t)kMP * kK * 2);       // 230.6 MB
  size_t wbf_o = alloc((size_t)kC * kK * 2);        // 1.2 MB
  size_t cnt_o = alloc((size_t)kR * kN * 4);        // 1.6 MB
  size_t deg_o = alloc((size_t)kN * 4);
  size_t cs_o  = alloc(256 * 4);
  size_t csq_o = alloc(256 * 4);
  size_t zend  = o;                                 // end of must-zero region
  size_t off_o = alloc((size_t)(kN + 1) * 4);
  size_t cur_o = alloc((size_t)kR * kN * 4);
  size_t eb_o  = alloc((size_t)kE * 2);             // u16 src records
  if (o > ws_size) {
    fprintf(stderr, "[RGCN kernel] ws too small: need %zu have %zu\n", o, ws_size);
    return;
  }

  unsigned short* A    = (unsigned short*)(ws + a_o);
  unsigned short* wbfT = (unsigned short*)(ws + wbf_o);
  int*   cnt  = (int*)(ws + cnt_o);
  int*   deg  = (int*)(ws + deg_o);
  float* cs   = (float*)(ws + cs_o);
  float* csq  = (float*)(ws + csq_o);
  int*   offp = (int*)(ws + off_o);
  int*   cur  = (int*)(ws + cur_o);
  unsigned short* ebuf = (unsigned short*)(ws + eb_o);

  hipMemsetAsync(ws + cnt_o, 0, zend - cnt_o, stream);                       // cnt/deg/cs/csq
  hipMemsetAsync(ws + a_o + (size_t)kN * kK * 2, 0,
                 (size_t)(kMP - kN) * kK * 2, stream);                       // A pad rows
  k_count<<<(kE + 255) / 256, 256, 0, stream>>>(ei, ea, cnt, deg);
  k_convert_x<<<(kN * kC / 4) / 256, 256, 0, stream>>>(x, A);
  k_convert_w<<<(kC * kK + 255) / 256, 256, 0, stream>>>(W, root, wbfT);
  k_scan<<<1, 1024, 0, stream>>>(deg, offp);
  k_grp<<<(kN + 255) / 256, 256, 0, stream>>>(offp, cnt, cur);
  k_fill<<<(kE + 255) / 256, 256, 0, stream>>>(ei, ea, cur, ebuf);
  k_agg<<<(kN + 3) / 4, 256, 0, stream>>>(ebuf, offp, cnt, A);
  k_gemm<<<dim3(kC / 128, kMP / 128), 256, 0, stream>>>(A, wbfT, out, bias, cs, csq);
  k_final<<<(kN * kC / 4) / 256, 256, 0, stream>>>(out, x, cs, csq, bias, gamma, beta, prelu);
}

// Round 7
// 525.163 us; speedup vs baseline: 1.0146x; 1.0146x over previous
//
#include <hip/hip_runtime.h>
#include <cstdio>
#include <cstdint>

// RGCN block, aggregation-first:
//   M[dst, r*256+ch] = mean_{edges (src->dst, rel=r)} x_bf16[src, ch]
//   A = [M | x_bf16]  (50048 x 2304),  B = [W_0..W_7 ; root]  (2304 x 256)
//   h = A @ B + bias  -> BN(batch stats) -> PReLU -> + x
// GEMM: M64xN64 tiles (3128 blocks, 12/CU for latency hiding), K-step 64,
// A+B LDS double-buffer (32 KB -> 5 blocks/CU), ALL loop global traffic via
// global_load_lds so the counted s_waitcnt vmcnt(4) keeps next tile in flight
// (round-6 lesson: any direct global read in the loop forces a full drain).
// NOTE: harness delivers integer inputs as int32 (edge_index int64 -> const int*).

constexpr int kN  = 50000;   // nodes
constexpr int kE  = 800000;  // edges
constexpr int kR  = 8;       // relations
constexpr int kC  = 256;     // channels
constexpr int kMP = 50048;   // padded rows (782*64)
constexpr int kK  = 2304;    // GEMM K = 8*256 + 256

typedef __attribute__((ext_vector_type(8))) short bf16x8;
typedef __attribute__((ext_vector_type(4))) float f32x4;
typedef __attribute__((ext_vector_type(2))) unsigned int u32x2;

__device__ __forceinline__ unsigned short f2bf(float f) {
  unsigned u = __builtin_bit_cast(unsigned, f);
  u = u + 0x7FFFu + ((u >> 16) & 1u);
  return (unsigned short)(u >> 16);
}
__device__ __forceinline__ float bf2f(unsigned short s) {
  unsigned u = ((unsigned)s) << 16;
  return __builtin_bit_cast(float, u);
}
__device__ __forceinline__ void gload16(const void* g, void* l) {
  __builtin_amdgcn_global_load_lds((__attribute__((address_space(1))) const void*)g,
                                   (__attribute__((address_space(3))) void*)l, 16, 0, 0);
}

// ---- per-edge counts: cnt[rel*N+dst], deg[dst] ----
__global__ void k_count(const int* __restrict__ ei, const float* __restrict__ ea,
                        int* __restrict__ cnt, int* __restrict__ deg) {
  int e = blockIdx.x * blockDim.x + threadIdx.x;
  if (e >= kE) return;
  int dst = ei[kE + e];
  int rel = (int)ea[(size_t)e * 5 + 4];
  if ((unsigned)dst >= (unsigned)kN || (unsigned)rel >= (unsigned)kR) return;
  atomicAdd(&cnt[rel * kN + dst], 1);
  atomicAdd(&deg[dst], 1);
}

// ---- convert x -> bf16 into A cols 2048..2303 ----
__global__ void k_convert_x(const float* __restrict__ x, unsigned short* __restrict__ A) {
  int i = (blockIdx.x * blockDim.x + threadIdx.x) * 4;
  if (i >= kN * kC) return;
  int row = i >> 8, col = i & 255;
  float4 v = *(const float4*)(x + i);
  ushort4 o;
  o.x = f2bf(v.x); o.y = f2bf(v.y); o.z = f2bf(v.z); o.w = f2bf(v.w);
  *(ushort4*)(A + (size_t)row * kK + 2048 + col) = o;
}

// ---- convert W+root -> bf16 transposed: wbfT[c][k], k<2048: W[k>>8][k&255][c]; else root[k-2048][c] ----
__global__ void k_convert_w(const float* __restrict__ W, const float* __restrict__ root,
                            unsigned short* __restrict__ wbfT) {
  int t = blockIdx.x * blockDim.x + threadIdx.x;   // c*kK + k
  if (t >= kC * kK) return;
  int c = t / kK, k = t - c * kK;
  float v;
  if (k < kR * kC) {
    int r = k >> 8, kk = k & 255;
    v = W[(size_t)r * kC * kC + (size_t)kk * kC + c];
  } else {
    v = root[(size_t)(k - kR * kC) * kC + c];
  }
  wbfT[(size_t)c * kK + k] = f2bf(v);
}

// ---- exclusive scan of deg -> off ----
__global__ __launch_bounds__(1024) void k_scan(const int* __restrict__ deg, int* __restrict__ off) {
  __shared__ int wsum[16];
  int t = threadIdx.x;
  const int slab = (kN + 1023) / 1024;   // 49
  int lo = t * slab, hi = min(lo + slab, kN);
  int s = 0;
  for (int i = lo; i < hi; ++i) s += deg[i];
  int incl = s;
#pragma unroll
  for (int d = 1; d < 64; d <<= 1) {
    int v = __shfl_up(incl, d);
    if ((t & 63) >= d) incl += v;
  }
  if ((t & 63) == 63) wsum[t >> 6] = incl;
  __syncthreads();
  if (t == 0) {
    int run = 0;
#pragma unroll
    for (int i = 0; i < 16; ++i) { int tmp = wsum[i]; wsum[i] = run; run += tmp; }
  }
  __syncthreads();
  int base = wsum[t >> 6] + incl - s;
  for (int i = lo; i < hi; ++i) { off[i] = base; base += deg[i]; }
  if (t == 1023) off[kN] = base;
}

// ---- per-(rel,dst) group cursors ----
__global__ void k_grp(const int* __restrict__ off, const int* __restrict__ cnt,
                      int* __restrict__ cur) {
  int t = blockIdx.x * blockDim.x + threadIdx.x;
  if (t >= kN) return;
  int o = off[t];
#pragma unroll
  for (int r = 0; r < kR; ++r) { cur[r * kN + t] = o; o += cnt[r * kN + t]; }
}

// ---- fill CSR edge records (u16 src), grouped (dst, rel) ----
__global__ void k_fill(const int* __restrict__ ei, const float* __restrict__ ea,
                       int* __restrict__ cur, unsigned short* __restrict__ ebuf) {
  int e = blockIdx.x * blockDim.x + threadIdx.x;
  if (e >= kE) return;
  int src = ei[e];
  int dst = ei[kE + e];
  int rel = (int)ea[(size_t)e * 5 + 4];
  if ((unsigned)dst >= (unsigned)kN || (unsigned)rel >= (unsigned)kR) return;
  int pos = atomicAdd(&cur[rel * kN + dst], 1);
  ebuf[pos] = (unsigned short)src;
}

// ---- aggregation: 1 wave per dst; mean x[src] per relation -> A cols 0..2047 (nontemporal) ----
__global__ __launch_bounds__(256) void k_agg(const unsigned short* __restrict__ ebuf,
                                             const int* __restrict__ off,
                                             const int* __restrict__ cnt,
                                             unsigned short* A) {
  int dst = blockIdx.x * 4 + (threadIdx.x >> 6);
  if (dst >= kN) return;
  int lane = threadIdx.x & 63;
  int e = off[dst];
  const unsigned short* xcols = A + 2048 + lane * 4;   // x region of A
  unsigned short* mrow = A + (size_t)dst * kK + lane * 4;
#pragma unroll
  for (int r = 0; r < kR; ++r) {
    int c = cnt[r * kN + dst];
    float s0 = 0.f, s1 = 0.f, s2 = 0.f, s3 = 0.f;
    for (int k = 0; k < c; ++k) {
      int src = ebuf[e + k];
      ushort4 v = *(const ushort4*)(xcols + (size_t)src * kK);
      s0 += bf2f(v.x); s1 += bf2f(v.y); s2 += bf2f(v.z); s3 += bf2f(v.w);
    }
    e += c;
    float sc = c > 0 ? 1.f / (float)c : 0.f;
    unsigned lo = (unsigned)f2bf(s0 * sc) | ((unsigned)f2bf(s1 * sc) << 16);
    unsigned hi = (unsigned)f2bf(s2 * sc) | ((unsigned)f2bf(s3 * sc) << 16);
    u32x2 pk = {lo, hi};
    __builtin_nontemporal_store(pk, (u32x2*)(mrow + r * 256));   // don't evict x from L3
  }
}

// ---- GEMM [kMP x 2304] @ [2304 x 256] -> d_out f32 (+bias), fused BN column stats ----
// M64xN64 per block; A+B LDS dbuf, XOR-swizzled content; counted vmcnt(4).
__global__ __launch_bounds__(256) void k_gemm(const unsigned short* __restrict__ A,
                                              const unsigned short* __restrict__ wbfT,
                                              float* __restrict__ out,
                                              const float* __restrict__ bias,
                                              float* __restrict__ cs,
                                              float* __restrict__ csq) {
  __shared__ __align__(16) unsigned short As[2][64 * 64];  // 2 x 8 KB, swizzled content
  __shared__ __align__(16) unsigned short Bs[2][64 * 64];  // 2 x 8 KB, swizzled content
  const int tid = threadIdx.x;
  const int lane = tid & 63, wv = tid >> 6;
  const int n0 = blockIdx.x * 64, m0 = blockIdx.y * 64;
  const int wm = wv >> 1, wn = wv & 1;  // 2x2 wave grid, 32x32 out each
  f32x4 acc[2][2] = {};

  const int srow = (lane >> 3);                         // 0..7 == row&7
  const int skk  = ((lane & 7) ^ srow) * 8;             // pre-swizzled global k-chunk

#define STAGE(buf, kt)                                                            \
  {                                                                               \
    const int kb_ = (kt) * 64;                                                    \
    _Pragma("unroll")                                                             \
    for (int c = 0; c < 2; ++c) {                                                 \
      int row_ = c * 32 + wv * 8 + srow;                                          \
      gload16(A    + (size_t)(m0 + row_) * kK + kb_ + skk,                        \
              &As[buf][c * 2048 + wv * 512]);                                     \
      gload16(wbfT + (size_t)(n0 + row_) * kK + kb_ + skk,                        \
              &Bs[buf][c * 2048 + wv * 512]);                                     \
    }                                                                             \
  }

  STAGE(0, 0);
  constexpr int NT = kK / 64;  // 36
  for (int t = 0; t < NT; ++t) {
    const int buf = t & 1;
    if (t + 1 < NT) {
      STAGE(buf ^ 1, t + 1);
      asm volatile("s_waitcnt vmcnt(4)" ::: "memory");   // own tile-t loads retired; t+1 in flight
    } else {
      asm volatile("s_waitcnt vmcnt(0)" ::: "memory");
    }
    __builtin_amdgcn_s_barrier();
    __builtin_amdgcn_sched_barrier(0);
#pragma unroll
    for (int kk = 0; kk < 64; kk += 32) {
      const int koff = kk + (lane >> 4) * 8;
      bf16x8 a[2], b[2];
#pragma unroll
      for (int i = 0; i < 2; ++i) {
        int ra = wm * 32 + i * 16 + (lane & 15);
        int rb = wn * 32 + i * 16 + (lane & 15);
        unsigned ba = (unsigned)(koff * 2) ^ (unsigned)((ra & 7) << 4);
        unsigned bb = (unsigned)(koff * 2) ^ (unsigned)((rb & 7) << 4);
        a[i] = *(const bf16x8*)((const char*)As[buf] + ra * 128 + ba);
        b[i] = *(const bf16x8*)((const char*)Bs[buf] + rb * 128 + bb);
      }
#pragma unroll
      for (int i = 0; i < 2; ++i)
#pragma unroll
        for (int j = 0; j < 2; ++j)
          acc[i][j] = __builtin_amdgcn_mfma_f32_16x16x32_bf16(a[i], b[j], acc[i][j], 0, 0, 0);
    }
    __builtin_amdgcn_s_barrier();            // compute done before next stage overwrites buf
    __builtin_amdgcn_sched_barrier(0);
  }
#undef STAGE

  // C/D layout: col = lane&15, row = (lane>>4)*4 + q.  Stats on raw acc (bias-free;
  // pad rows have zero acc so they contribute nothing to the sums).
#pragma unroll
  for (int j = 0; j < 2; ++j) {
    int col = n0 + wn * 32 + j * 16 + (lane & 15);
    float bv = bias[col];
    float s = 0.f, ss = 0.f;
#pragma unroll
    for (int i = 0; i < 2; ++i) {
      int rb = m0 + wm * 32 + i * 16 + (lane >> 4) * 4;
#pragma unroll
      for (int q = 0; q < 4; ++q) {
        float v = acc[i][j][q];
        s += v; ss += v * v;
        int row = rb + q;
        if (row < kN) out[(size_t)row * kC + col] = v + bv;
      }
    }
    s  += __shfl_xor(s, 16);  s  += __shfl_xor(s, 32);
    ss += __shfl_xor(ss, 16); ss += __shfl_xor(ss, 32);
    if (lane < 16) { atomicAdd(&cs[col], s); atomicAdd(&csq[col], ss); }
  }
}

// ---- BN normalize + PReLU + residual (stats are bias-free; shift mu by bias) ----
__global__ void k_final(float* __restrict__ h, const float* __restrict__ x,
                        const float* __restrict__ cs, const float* __restrict__ csq,
                        const float* __restrict__ bias,
                        const float* __restrict__ gamma, const float* __restrict__ beta,
                        const float* __restrict__ prelu) {
  int idx = (blockIdx.x * blockDim.x + threadIdx.x) * 4;
  if (idx >= kN * kC) return;
  int col = idx & 255;
  const float inv_n = 1.0f / (float)kN;
  float a = prelu[0];
  float4 hv = *(float4*)(h + idx);
  float4 xv = *(const float4*)(x + idx);
  float hr[4] = {hv.x, hv.y, hv.z, hv.w};
  float xr[4] = {xv.x, xv.y, xv.z, xv.w};
#pragma unroll
  for (int j = 0; j < 4; ++j) {
    int c = col + j;
    float mu_raw = cs[c] * inv_n;
    float var = csq[c] * inv_n - mu_raw * mu_raw;
    float mu  = mu_raw + bias[c];          // h was stored with bias added
    float k   = gamma[c] * rsqrtf(var + 1e-5f);
    float v   = (hr[j] - mu) * k + beta[c];
    v = v > 0.f ? v : a * v;
    hr[j] = v + xr[j];
  }
  *(float4*)(h + idx) = make_float4(hr[0], hr[1], hr[2], hr[3]);
}

extern "C" void kernel_launch(void* const* d_in, const int* in_sizes, int n_in,
                              void* d_out, int out_size, void* d_ws, size_t ws_size,
                              hipStream_t stream) {
  const float* x     = (const float*)d_in[0];
  const int*   ei    = (const int*)d_in[1];     // int64 in ref -> int32 from harness
  const float* ea    = (const float*)d_in[2];
  const float* W     = (const float*)d_in[3];
  const float* root  = (const float*)d_in[4];
  const float* bias  = (const float*)d_in[5];
  const float* gamma = (const float*)d_in[6];
  const float* beta  = (const float*)d_in[7];
  const float* prelu = (const float*)d_in[8];
  float* out = (float*)d_out;
  char* ws = (char*)d_ws;

  size_t o = 0;
  auto alloc = [&](size_t sz) { size_t r = o; o += (sz + 255) & ~(size_t)255; return r; };
  size_t a_o   = alloc((size_t)kMP * kK * 2);       // 230.6 MB
  size_t wbf_o = alloc((size_t)kC * kK * 2);        // 1.2 MB
  size_t cnt_o = alloc((size_t)kR * kN * 4);        // 1.6 MB
  size_t deg_o = alloc((size_t)kN * 4);
  size_t cs_o  = alloc(256 * 4);
  size_t csq_o = alloc(256 * 4);
  size_t zend  = o;                                 // end of must-zero region
  size_t off_o = alloc((size_t)(kN + 1) * 4);
  size_t cur_o = alloc((size_t)kR * kN * 4);
  size_t eb_o  = alloc((size_t)kE * 2);             // u16 src records
  if (o > ws_size) {
    fprintf(stderr, "[RGCN kernel] ws too small: need %zu have %zu\n", o, ws_size);
    return;
  }

  unsigned short* A    = (unsigned short*)(ws + a_o);
  unsigned short* wbfT = (unsigned short*)(ws + wbf_o);
  int*   cnt  = (int*)(ws + cnt_o);
  int*   deg  = (int*)(ws + deg_o);
  float* cs   = (float*)(ws + cs_o);
  float* csq  = (float*)(ws + csq_o);
  int*   offp = (int*)(ws + off_o);
  int*   cur  = (int*)(ws + cur_o);
  unsigned short* ebuf = (unsigned short*)(ws + eb_o);

  hipMemsetAsync(ws + cnt_o, 0, zend - cnt_o, stream);                       // cnt/deg/cs/csq
  hipMemsetAsync(ws + a_o + (size_t)kN * kK * 2, 0,
                 (size_t)(kMP - kN) * kK * 2, stream);                       // A pad rows
  k_count<<<(kE + 255) / 256, 256, 0, stream>>>(ei, ea, cnt, deg);
  k_convert_x<<<(kN * kC / 4) / 256, 256, 0, stream>>>(x, A);
  k_convert_w<<<(kC * kK + 255) / 256, 256, 0, stream>>>(W, root, wbfT);
  k_scan<<<1, 1024, 0, stream>>>(deg, offp);
  k_grp<<<(kN + 255) / 256, 256, 0, stream>>>(offp, cnt, cur);
  k_fill<<<(kE + 255) / 256, 256, 0, stream>>>(ei, ea, cur, ebuf);
  k_agg<<<(kN + 3) / 4, 256, 0, stream>>>(ebuf, offp, cnt, A);
  k_gemm<<<dim3(kC / 64, kMP / 64), 256, 0, stream>>>(A, wbfT, out, bias, cs, csq);
  k_final<<<(kN * kC / 4) / 256, 256, 0, stream>>>(out, x, cs, csq, bias, gamma, beta, prelu);
}

// Round 8
// 406.942 us; speedup vs baseline: 1.3093x; 1.2905x over previous
//
#include <hip/hip_runtime.h>
#include <cstdio>
#include <cstdint>

// RGCN block, aggregation-first:
//   M[dst, r*256+ch] = mean_{edges (src->dst, rel=r)} x_bf16[src, ch]
//   A = [M | x_bf16]  (50048 x 2304),  B = [W_0..W_7 ; root]  (2304 x 256)
//   h = A @ B + bias  -> BN(batch stats) -> PReLU -> + x
// GEMM: M64xN64 tiles, K-step 64, A+B LDS dbuf, counted vmcnt(4) pipeline,
// bijective XCD-chunk swizzle so the 4 N-blocks of an M-row share one XCD L2
// (round-7: consecutive dispatch put them on 4 XCDs -> A fetched 2x from HBM).
// CSR group bases via wave-scan + global atomic cursor (no sorted scan needed;
// group order in ebuf is irrelevant, only per-group contiguity matters).
// NOTE: harness delivers integer inputs as int32 (edge_index int64 -> const int*).

constexpr int kN  = 50000;   // nodes
constexpr int kE  = 800000;  // edges
constexpr int kR  = 8;       // relations
constexpr int kC  = 256;     // channels
constexpr int kMP = 50048;   // padded rows (782*64)
constexpr int kK  = 2304;    // GEMM K = 8*256 + 256
constexpr int kWG = (kMP / 64) * (kC / 64);  // 3128 = 8*391

typedef __attribute__((ext_vector_type(8))) short bf16x8;
typedef __attribute__((ext_vector_type(4))) float f32x4;
typedef __attribute__((ext_vector_type(2))) unsigned int u32x2;

__device__ __forceinline__ unsigned short f2bf(float f) {
  unsigned u = __builtin_bit_cast(unsigned, f);
  u = u + 0x7FFFu + ((u >> 16) & 1u);
  return (unsigned short)(u >> 16);
}
__device__ __forceinline__ float bf2f(unsigned short s) {
  unsigned u = ((unsigned)s) << 16;
  return __builtin_bit_cast(float, u);
}
__device__ __forceinline__ void gload16(const void* g, void* l) {
  __builtin_amdgcn_global_load_lds((__attribute__((address_space(1))) const void*)g,
                                   (__attribute__((address_space(3))) void*)l, 16, 0, 0);
}

// ---- per-edge counts: cnt[rel*N+dst] ----
__global__ void k_count(const int* __restrict__ ei, const float* __restrict__ ea,
                        int* __restrict__ cnt) {
  int e = blockIdx.x * blockDim.x + threadIdx.x;
  if (e >= kE) return;
  int dst = ei[kE + e];
  int rel = (int)ea[(size_t)e * 5 + 4];
  if ((unsigned)dst >= (unsigned)kN || (unsigned)rel >= (unsigned)kR) return;
  atomicAdd(&cnt[rel * kN + dst], 1);
}

// ---- convert x -> bf16 into A cols 2048..2303 ----
__global__ void k_convert_x(const float* __restrict__ x, unsigned short* __restrict__ A) {
  int i = (blockIdx.x * blockDim.x + threadIdx.x) * 4;
  if (i >= kN * kC) return;
  int row = i >> 8, col = i & 255;
  float4 v = *(const float4*)(x + i);
  ushort4 o;
  o.x = f2bf(v.x); o.y = f2bf(v.y); o.z = f2bf(v.z); o.w = f2bf(v.w);
  *(ushort4*)(A + (size_t)row * kK + 2048 + col) = o;
}

// ---- convert W+root -> bf16 transposed: wbfT[c][k], k<2048: W[k>>8][k&255][c]; else root[k-2048][c] ----
__global__ void k_convert_w(const float* __restrict__ W, const float* __restrict__ root,
                            unsigned short* __restrict__ wbfT) {
  int t = blockIdx.x * blockDim.x + threadIdx.x;   // c*kK + k
  if (t >= kC * kK) return;
  int c = t / kK, k = t - c * kK;
  float v;
  if (k < kR * kC) {
    int r = k >> 8, kk = k & 255;
    v = W[(size_t)r * kC * kC + (size_t)kk * kC + c];
  } else {
    v = root[(size_t)(k - kR * kC) * kC + c];
  }
  wbfT[(size_t)c * kK + k] = f2bf(v);
}

// ---- group bases: wave-scan of per-dst group sizes + one atomicAdd per wave ----
// off[dst] = base of dst's 8 groups in ebuf; cur[r*kN+dst] = per-(rel,dst) cursor.
__global__ void k_grp(const int* __restrict__ cnt, int* __restrict__ cursor,
                      int* __restrict__ off, int* __restrict__ cur) {
  int t = blockIdx.x * blockDim.x + threadIdx.x;
  int lane = threadIdx.x & 63;
  int c[kR];
  int gsz = 0;
  if (t < kN) {
#pragma unroll
    for (int r = 0; r < kR; ++r) { c[r] = cnt[r * kN + t]; gsz += c[r]; }
  } else {
#pragma unroll
    for (int r = 0; r < kR; ++r) c[r] = 0;
  }
  int incl = gsz;
#pragma unroll
  for (int d = 1; d < 64; d <<= 1) {
    int v = __shfl_up(incl, d);
    if (lane >= d) incl += v;
  }
  int wtot = __shfl(incl, 63);
  int base = 0;
  if (lane == 63) base = atomicAdd(cursor, wtot);
  base = __shfl(base, 63);
  if (t < kN) {
    int o = base + incl - gsz;
    off[t] = o;
#pragma unroll
    for (int r = 0; r < kR; ++r) { cur[r * kN + t] = o; o += c[r]; }
  }
}

// ---- fill CSR edge records (u16 src), grouped (dst, rel) ----
__global__ void k_fill(const int* __restrict__ ei, const float* __restrict__ ea,
                       int* __restrict__ cur, unsigned short* __restrict__ ebuf) {
  int e = blockIdx.x * blockDim.x + threadIdx.x;
  if (e >= kE) return;
  int src = ei[e];
  int dst = ei[kE + e];
  int rel = (int)ea[(size_t)e * 5 + 4];
  if ((unsigned)dst >= (unsigned)kN || (unsigned)rel >= (unsigned)kR) return;
  int pos = atomicAdd(&cur[rel * kN + dst], 1);
  ebuf[pos] = (unsigned short)src;
}

// ---- aggregation: 1 wave per dst; mean x[src] per relation -> A cols 0..2047 (nontemporal) ----
__global__ __launch_bounds__(256) void k_agg(const unsigned short* __restrict__ ebuf,
                                             const int* __restrict__ off,
                                             const int* __restrict__ cnt,
                                             unsigned short* A) {
  int dst = blockIdx.x * 4 + (threadIdx.x >> 6);
  if (dst >= kN) return;
  int lane = threadIdx.x & 63;
  int e = off[dst];
  const unsigned short* xcols = A + 2048 + lane * 4;   // x region of A
  unsigned short* mrow = A + (size_t)dst * kK + lane * 4;
#pragma unroll
  for (int r = 0; r < kR; ++r) {
    int c = cnt[r * kN + dst];
    float s0 = 0.f, s1 = 0.f, s2 = 0.f, s3 = 0.f;
    for (int k = 0; k < c; ++k) {
      int src = ebuf[e + k];
      ushort4 v = *(const ushort4*)(xcols + (size_t)src * kK);
      s0 += bf2f(v.x); s1 += bf2f(v.y); s2 += bf2f(v.z); s3 += bf2f(v.w);
    }
    e += c;
    float sc = c > 0 ? 1.f / (float)c : 0.f;
    unsigned lo = (unsigned)f2bf(s0 * sc) | ((unsigned)f2bf(s1 * sc) << 16);
    unsigned hi = (unsigned)f2bf(s2 * sc) | ((unsigned)f2bf(s3 * sc) << 16);
    u32x2 pk = {lo, hi};
    __builtin_nontemporal_store(pk, (u32x2*)(mrow + r * 256));   // don't evict x from L3
  }
}

// ---- GEMM [kMP x 2304] @ [2304 x 256] -> d_out f32 (+bias), fused BN column stats ----
// M64xN64 per block; A+B LDS dbuf, XOR-swizzled content; counted vmcnt(4);
// bijective XCD-chunk swizzle (3128 = 8*391).
__global__ __launch_bounds__(256) void k_gemm(const unsigned short* __restrict__ A,
                                              const unsigned short* __restrict__ wbfT,
                                              float* __restrict__ out,
                                              const float* __restrict__ bias,
                                              float* __restrict__ cs,
                                              float* __restrict__ csq) {
  __shared__ __align__(16) unsigned short As[2][64 * 64];  // 2 x 8 KB, swizzled content
  __shared__ __align__(16) unsigned short Bs[2][64 * 64];  // 2 x 8 KB, swizzled content
  const int tid = threadIdx.x;
  const int lane = tid & 63, wv = tid >> 6;
  // XCD swizzle: consecutive wgid (same M-row's 4 N-blocks) land on one XCD's L2.
  const int bid  = blockIdx.x;
  const int wgid = (bid & 7) * (kWG / 8) + (bid >> 3);
  const int n0 = (wgid & 3) * 64, m0 = (wgid >> 2) * 64;
  const int wm = wv >> 1, wn = wv & 1;  // 2x2 wave grid, 32x32 out each
  f32x4 acc[2][2] = {};

  const int srow = (lane >> 3);                         // 0..7 == row&7
  const int skk  = ((lane & 7) ^ srow) * 8;             // pre-swizzled global k-chunk

#define STAGE(buf, kt)                                                            \
  {                                                                               \
    const int kb_ = (kt) * 64;                                                    \
    _Pragma("unroll")                                                             \
    for (int c = 0; c < 2; ++c) {                                                 \
      int row_ = c * 32 + wv * 8 + srow;                                          \
      gload16(A    + (size_t)(m0 + row_) * kK + kb_ + skk,                        \
              &As[buf][c * 2048 + wv * 512]);                                     \
      gload16(wbfT + (size_t)(n0 + row_) * kK + kb_ + skk,                        \
              &Bs[buf][c * 2048 + wv * 512]);                                     \
    }                                                                             \
  }

  STAGE(0, 0);
  constexpr int NT = kK / 64;  // 36
  for (int t = 0; t < NT; ++t) {
    const int buf = t & 1;
    if (t + 1 < NT) {
      STAGE(buf ^ 1, t + 1);
      asm volatile("s_waitcnt vmcnt(4)" ::: "memory");   // own tile-t loads retired; t+1 in flight
    } else {
      asm volatile("s_waitcnt vmcnt(0)" ::: "memory");
    }
    __builtin_amdgcn_s_barrier();
    __builtin_amdgcn_sched_barrier(0);
#pragma unroll
    for (int kk = 0; kk < 64; kk += 32) {
      const int koff = kk + (lane >> 4) * 8;
      bf16x8 a[2], b[2];
#pragma unroll
      for (int i = 0; i < 2; ++i) {
        int ra = wm * 32 + i * 16 + (lane & 15);
        int rb = wn * 32 + i * 16 + (lane & 15);
        unsigned ba = (unsigned)(koff * 2) ^ (unsigned)((ra & 7) << 4);
        unsigned bb = (unsigned)(koff * 2) ^ (unsigned)((rb & 7) << 4);
        a[i] = *(const bf16x8*)((const char*)As[buf] + ra * 128 + ba);
        b[i] = *(const bf16x8*)((const char*)Bs[buf] + rb * 128 + bb);
      }
#pragma unroll
      for (int i = 0; i < 2; ++i)
#pragma unroll
        for (int j = 0; j < 2; ++j)
          acc[i][j] = __builtin_amdgcn_mfma_f32_16x16x32_bf16(a[i], b[j], acc[i][j], 0, 0, 0);
    }
    __builtin_amdgcn_s_barrier();            // compute done before next stage overwrites buf
    __builtin_amdgcn_sched_barrier(0);
  }
#undef STAGE

  // C/D layout: col = lane&15, row = (lane>>4)*4 + q.  Stats on raw acc (bias-free;
  // pad rows have zero acc so they contribute nothing to the sums).
#pragma unroll
  for (int j = 0; j < 2; ++j) {
    int col = n0 + wn * 32 + j * 16 + (lane & 15);
    float bv = bias[col];
    float s = 0.f, ss = 0.f;
#pragma unroll
    for (int i = 0; i < 2; ++i) {
      int rb = m0 + wm * 32 + i * 16 + (lane >> 4) * 4;
#pragma unroll
      for (int q = 0; q < 4; ++q) {
        float v = acc[i][j][q];
        s += v; ss += v * v;
        int row = rb + q;
        if (row < kN) out[(size_t)row * kC + col] = v + bv;
      }
    }
    s  += __shfl_xor(s, 16);  s  += __shfl_xor(s, 32);
    ss += __shfl_xor(ss, 16); ss += __shfl_xor(ss, 32);
    if (lane < 16) { atomicAdd(&cs[col], s); atomicAdd(&csq[col], ss); }
  }
}

// ---- BN normalize + PReLU + residual (stats are bias-free; shift mu by bias) ----
__global__ void k_final(float* __restrict__ h, const float* __restrict__ x,
                        const float* __restrict__ cs, const float* __restrict__ csq,
                        const float* __restrict__ bias,
                        const float* __restrict__ gamma, const float* __restrict__ beta,
                        const float* __restrict__ prelu) {
  int idx = (blockIdx.x * blockDim.x + threadIdx.x) * 4;
  if (idx >= kN * kC) return;
  int col = idx & 255;
  const float inv_n = 1.0f / (float)kN;
  float a = prelu[0];
  float4 hv = *(float4*)(h + idx);
  float4 xv = *(const float4*)(x + idx);
  float hr[4] = {hv.x, hv.y, hv.z, hv.w};
  float xr[4] = {xv.x, xv.y, xv.z, xv.w};
#pragma unroll
  for (int j = 0; j < 4; ++j) {
    int c = col + j;
    float mu_raw = cs[c] * inv_n;
    float var = csq[c] * inv_n - mu_raw * mu_raw;
    float mu  = mu_raw + bias[c];          // h was stored with bias added
    float k   = gamma[c] * rsqrtf(var + 1e-5f);
    float v   = (hr[j] - mu) * k + beta[c];
    v = v > 0.f ? v : a * v;
    hr[j] = v + xr[j];
  }
  *(float4*)(h + idx) = make_float4(hr[0], hr[1], hr[2], hr[3]);
}

extern "C" void kernel_launch(void* const* d_in, const int* in_sizes, int n_in,
                              void* d_out, int out_size, void* d_ws, size_t ws_size,
                              hipStream_t stream) {
  const float* x     = (const float*)d_in[0];
  const int*   ei    = (const int*)d_in[1];     // int64 in ref -> int32 from harness
  const float* ea    = (const float*)d_in[2];
  const float* W     = (const float*)d_in[3];
  const float* root  = (const float*)d_in[4];
  const float* bias  = (const float*)d_in[5];
  const float* gamma = (const float*)d_in[6];
  const float* beta  = (const float*)d_in[7];
  const float* prelu = (const float*)d_in[8];
  float* out = (float*)d_out;
  char* ws = (char*)d_ws;

  size_t o = 0;
  auto alloc = [&](size_t sz) { size_t r = o; o += (sz + 255) & ~(size_t)255; return r; };
  size_t a_o    = alloc((size_t)kMP * kK * 2);       // 230.6 MB
  size_t wbf_o  = alloc((size_t)kC * kK * 2);        // 1.2 MB
  size_t cnt_o  = alloc((size_t)kR * kN * 4);        // 1.6 MB
  size_t cs_o   = alloc(256 * 4);
  size_t csq_o  = alloc(256 * 4);
  size_t csr_o  = alloc(256);                        // global cursor (1 int)
  size_t zend   = o;                                 // end of must-zero region
  size_t off_o  = alloc((size_t)kN * 4);
  size_t cur_o  = alloc((size_t)kR * kN * 4);
  size_t eb_o   = alloc((size_t)kE * 2);             // u16 src records
  if (o > ws_size) {
    fprintf(stderr, "[RGCN kernel] ws too small: need %zu have %zu\n", o, ws_size);
    return;
  }

  unsigned short* A    = (unsigned short*)(ws + a_o);
  unsigned short* wbfT = (unsigned short*)(ws + wbf_o);
  int*   cnt    = (int*)(ws + cnt_o);
  float* cs     = (float*)(ws + cs_o);
  float* csq    = (float*)(ws + csq_o);
  int*   cursor = (int*)(ws + csr_o);
  int*   offp   = (int*)(ws + off_o);
  int*   cur    = (int*)(ws + cur_o);
  unsigned short* ebuf = (unsigned short*)(ws + eb_o);

  hipMemsetAsync(ws + cnt_o, 0, zend - cnt_o, stream);                       // cnt/cs/csq/cursor
  hipMemsetAsync(ws + a_o + (size_t)kN * kK * 2, 0,
                 (size_t)(kMP - kN) * kK * 2, stream);                       // A pad rows
  k_count<<<(kE + 255) / 256, 256, 0, stream>>>(ei, ea, cnt);
  k_convert_x<<<(kN * kC / 4) / 256, 256, 0, stream>>>(x, A);
  k_convert_w<<<(kC * kK + 255) / 256, 256, 0, stream>>>(W, root, wbfT);
  k_grp<<<(kN + 255) / 256, 256, 0, stream>>>(cnt, cursor, offp, cur);
  k_fill<<<(kE + 255) / 256, 256, 0, stream>>>(ei, ea, cur, ebuf);
  k_agg<<<(kN + 3) / 4, 256, 0, stream>>>(ebuf, offp, cnt, A);
  k_gemm<<<kWG, 256, 0, stream>>>(A, wbfT, out, bias, cs, csq);
  k_final<<<(kN * kC / 4) / 256, 256, 0, stream>>>(out, x, cs, csq, bias, gamma, beta, prelu);
}

// Round 9
// 361.574 us; speedup vs baseline: 1.4736x; 1.1255x over previous
//
#include <hip/hip_runtime.h>
#include <cstdio>
#include <cstdint>

// RGCN block, aggregation-first:
//   M[dst, r*256+ch] = mean_{edges (src->dst, rel=r)} x_bf16[src, ch]
//   A = [M | x_bf16]  (50048 x 2304),  B = [W_0..W_7 ; root]  (2304 x 256)
//   h = A @ B + bias  -> BN(batch stats) -> PReLU -> + x
// GEMM: 128x128 tiles, 512 threads (8 waves, 2x4), K-step 64, A+B LDS dbuf
// (64 KB, 2 blocks/CU), counted vmcnt(4) pipeline, bijective XCD-chunk swizzle.
// Round-8 lesson: 64^2 tiling was vmem-INSTRUCTION-issue bound (115M gload_lds
// = 1.1/cy/CU); 128^2 halves staging instructions (57.5M).
// NOTE: harness delivers integer inputs as int32 (edge_index int64 -> const int*).

constexpr int kN  = 50000;   // nodes
constexpr int kE  = 800000;  // edges
constexpr int kR  = 8;       // relations
constexpr int kC  = 256;     // channels
constexpr int kMP = 50048;   // padded rows (391*128)
constexpr int kK  = 2304;    // GEMM K = 8*256 + 256
constexpr int kWG = (kMP / 128) * (kC / 128);  // 782 grid blocks

typedef __attribute__((ext_vector_type(8))) short bf16x8;
typedef __attribute__((ext_vector_type(4))) float f32x4;
typedef __attribute__((ext_vector_type(2))) unsigned int u32x2;

__device__ __forceinline__ unsigned short f2bf(float f) {
  unsigned u = __builtin_bit_cast(unsigned, f);
  u = u + 0x7FFFu + ((u >> 16) & 1u);
  return (unsigned short)(u >> 16);
}
__device__ __forceinline__ float bf2f(unsigned short s) {
  unsigned u = ((unsigned)s) << 16;
  return __builtin_bit_cast(float, u);
}
__device__ __forceinline__ void gload16(const void* g, void* l) {
  __builtin_amdgcn_global_load_lds((__attribute__((address_space(1))) const void*)g,
                                   (__attribute__((address_space(3))) void*)l, 16, 0, 0);
}

// ---- per-edge counts: cnt[rel*N+dst] ----
__global__ void k_count(const int* __restrict__ ei, const float* __restrict__ ea,
                        int* __restrict__ cnt) {
  int e = blockIdx.x * blockDim.x + threadIdx.x;
  if (e >= kE) return;
  int dst = ei[kE + e];
  int rel = (int)ea[(size_t)e * 5 + 4];
  if ((unsigned)dst >= (unsigned)kN || (unsigned)rel >= (unsigned)kR) return;
  atomicAdd(&cnt[rel * kN + dst], 1);
}

// ---- convert x -> bf16 into A cols 2048..2303 ----
__global__ void k_convert_x(const float* __restrict__ x, unsigned short* __restrict__ A) {
  int i = (blockIdx.x * blockDim.x + threadIdx.x) * 4;
  if (i >= kN * kC) return;
  int row = i >> 8, col = i & 255;
  float4 v = *(const float4*)(x + i);
  ushort4 o;
  o.x = f2bf(v.x); o.y = f2bf(v.y); o.z = f2bf(v.z); o.w = f2bf(v.w);
  *(ushort4*)(A + (size_t)row * kK + 2048 + col) = o;
}

// ---- convert W+root -> bf16 transposed: wbfT[c][k], k<2048: W[k>>8][k&255][c]; else root[k-2048][c] ----
__global__ void k_convert_w(const float* __restrict__ W, const float* __restrict__ root,
                            unsigned short* __restrict__ wbfT) {
  int t = blockIdx.x * blockDim.x + threadIdx.x;   // c*kK + k
  if (t >= kC * kK) return;
  int c = t / kK, k = t - c * kK;
  float v;
  if (k < kR * kC) {
    int r = k >> 8, kk = k & 255;
    v = W[(size_t)r * kC * kC + (size_t)kk * kC + c];
  } else {
    v = root[(size_t)(k - kR * kC) * kC + c];
  }
  wbfT[(size_t)c * kK + k] = f2bf(v);
}

// ---- group bases: wave-scan of per-dst group sizes + one atomicAdd per wave ----
__global__ void k_grp(const int* __restrict__ cnt, int* __restrict__ cursor,
                      int* __restrict__ off, int* __restrict__ cur) {
  int t = blockIdx.x * blockDim.x + threadIdx.x;
  int lane = threadIdx.x & 63;
  int c[kR];
  int gsz = 0;
  if (t < kN) {
#pragma unroll
    for (int r = 0; r < kR; ++r) { c[r] = cnt[r * kN + t]; gsz += c[r]; }
  } else {
#pragma unroll
    for (int r = 0; r < kR; ++r) c[r] = 0;
  }
  int incl = gsz;
#pragma unroll
  for (int d = 1; d < 64; d <<= 1) {
    int v = __shfl_up(incl, d);
    if (lane >= d) incl += v;
  }
  int wtot = __shfl(incl, 63);
  int base = 0;
  if (lane == 63) base = atomicAdd(cursor, wtot);
  base = __shfl(base, 63);
  if (t < kN) {
    int o = base + incl - gsz;
    off[t] = o;
#pragma unroll
    for (int r = 0; r < kR; ++r) { cur[r * kN + t] = o; o += c[r]; }
  }
}

// ---- fill CSR edge records (u16 src), grouped (dst, rel) ----
__global__ void k_fill(const int* __restrict__ ei, const float* __restrict__ ea,
                       int* __restrict__ cur, unsigned short* __restrict__ ebuf) {
  int e = blockIdx.x * blockDim.x + threadIdx.x;
  if (e >= kE) return;
  int src = ei[e];
  int dst = ei[kE + e];
  int rel = (int)ea[(size_t)e * 5 + 4];
  if ((unsigned)dst >= (unsigned)kN || (unsigned)rel >= (unsigned)kR) return;
  int pos = atomicAdd(&cur[rel * kN + dst], 1);
  ebuf[pos] = (unsigned short)src;
}

// ---- aggregation: 1 wave per dst; mean x[src] per relation -> A cols 0..2047 (nontemporal) ----
__global__ __launch_bounds__(256) void k_agg(const unsigned short* __restrict__ ebuf,
                                             const int* __restrict__ off,
                                             const int* __restrict__ cnt,
                                             unsigned short* A) {
  int dst = blockIdx.x * 4 + (threadIdx.x >> 6);
  if (dst >= kN) return;
  int lane = threadIdx.x & 63;
  int e = off[dst];
  const unsigned short* xcols = A + 2048 + lane * 4;   // x region of A
  unsigned short* mrow = A + (size_t)dst * kK + lane * 4;
#pragma unroll
  for (int r = 0; r < kR; ++r) {
    int c = cnt[r * kN + dst];
    float s0 = 0.f, s1 = 0.f, s2 = 0.f, s3 = 0.f;
    for (int k = 0; k < c; ++k) {
      int src = ebuf[e + k];
      ushort4 v = *(const ushort4*)(xcols + (size_t)src * kK);
      s0 += bf2f(v.x); s1 += bf2f(v.y); s2 += bf2f(v.z); s3 += bf2f(v.w);
    }
    e += c;
    float sc = c > 0 ? 1.f / (float)c : 0.f;
    unsigned lo = (unsigned)f2bf(s0 * sc) | ((unsigned)f2bf(s1 * sc) << 16);
    unsigned hi = (unsigned)f2bf(s2 * sc) | ((unsigned)f2bf(s3 * sc) << 16);
    u32x2 pk = {lo, hi};
    __builtin_nontemporal_store(pk, (u32x2*)(mrow + r * 256));   // don't evict x from L3
  }
}

// ---- GEMM [kMP x 2304] @ [2304 x 256] -> d_out f32 (+bias), fused BN column stats ----
// 128x128 per block, 8 waves (2 wm x 4 wn), each wave 64x32 out (acc[4][2]).
// A+B LDS dbuf (64 KB), XOR-swizzled content, counted vmcnt(4), XCD-chunk swizzle.
__global__ __launch_bounds__(512) void k_gemm(const unsigned short* __restrict__ A,
                                              const unsigned short* __restrict__ wbfT,
                                              float* __restrict__ out,
                                              const float* __restrict__ bias,
                                              float* __restrict__ cs,
                                              float* __restrict__ csq) {
  __shared__ __align__(16) unsigned short As[2][128 * 64];  // 2 x 16 KB, swizzled content
  __shared__ __align__(16) unsigned short Bs[2][128 * 64];  // 2 x 16 KB, swizzled content
  const int tid = threadIdx.x;
  const int lane = tid & 63, wv = tid >> 6;
  // bijective XCD-chunk swizzle (nwg=782: q=97, r=6): consecutive wgid -> same XCD,
  // so the 2 N-blocks of each M-row share that XCD's L2 for A.
  const int bid = blockIdx.x;
  const int xcd = bid & 7, idx = bid >> 3;
  const int wgid = (xcd < 6 ? xcd * 98 : 588 + (xcd - 6) * 97) + idx;
  const int n0 = (wgid & 1) * 128, m0 = (wgid >> 1) * 128;
  const int wm = wv >> 2, wn = wv & 3;  // 2x4 wave grid, 64x32 out each
  f32x4 acc[4][2] = {};

  const int lrow = tid >> 3;                            // 0..63 (row base within half-tile)
  const int skk  = ((tid & 7) ^ (lrow & 7)) * 8;        // pre-swizzled global k-chunk

#define STAGE(buf, kt)                                                            \
  {                                                                               \
    const int kb_ = (kt) * 64;                                                    \
    _Pragma("unroll")                                                             \
    for (int c = 0; c < 2; ++c) {                                                 \
      int l_   = tid + 512 * c;       /* 0..1023 */                               \
      int row_ = c * 64 + lrow;       /* 0..127  */                               \
      gload16(A    + (size_t)(m0 + row_) * kK + kb_ + skk, &As[buf][l_ * 8]);     \
      gload16(wbfT + (size_t)(n0 + row_) * kK + kb_ + skk, &Bs[buf][l_ * 8]);     \
    }                                                                             \
  }

  STAGE(0, 0);
  constexpr int NT = kK / 64;  // 36
  for (int t = 0; t < NT; ++t) {
    const int buf = t & 1;
    if (t + 1 < NT) {
      STAGE(buf ^ 1, t + 1);
      asm volatile("s_waitcnt vmcnt(4)" ::: "memory");   // own tile-t loads retired; t+1 in flight
    } else {
      asm volatile("s_waitcnt vmcnt(0)" ::: "memory");
    }
    __builtin_amdgcn_s_barrier();
    __builtin_amdgcn_sched_barrier(0);
#pragma unroll
    for (int kk = 0; kk < 64; kk += 32) {
      const int koff = kk + (lane >> 4) * 8;
      bf16x8 a[4], b[2];
#pragma unroll
      for (int i = 0; i < 4; ++i) {
        int ra = wm * 64 + i * 16 + (lane & 15);
        unsigned ba = (unsigned)(koff * 2) ^ (unsigned)((ra & 7) << 4);
        a[i] = *(const bf16x8*)((const char*)As[buf] + ra * 128 + ba);
      }
#pragma unroll
      for (int j = 0; j < 2; ++j) {
        int rb = wn * 32 + j * 16 + (lane & 15);
        unsigned bb = (unsigned)(koff * 2) ^ (unsigned)((rb & 7) << 4);
        b[j] = *(const bf16x8*)((const char*)Bs[buf] + rb * 128 + bb);
      }
#pragma unroll
      for (int i = 0; i < 4; ++i)
#pragma unroll
        for (int j = 0; j < 2; ++j)
          acc[i][j] = __builtin_amdgcn_mfma_f32_16x16x32_bf16(a[i], b[j], acc[i][j], 0, 0, 0);
    }
    __builtin_amdgcn_s_barrier();            // compute done before next stage overwrites buf
    __builtin_amdgcn_sched_barrier(0);
  }
#undef STAGE

  // C/D layout: col = lane&15, row = (lane>>4)*4 + q.  Stats on raw acc (bias-free;
  // pad rows have zero acc so they contribute nothing to the sums).
#pragma unroll
  for (int j = 0; j < 2; ++j) {
    int col = n0 + wn * 32 + j * 16 + (lane & 15);
    float bv = bias[col];
    float s = 0.f, ss = 0.f;
#pragma unroll
    for (int i = 0; i < 4; ++i) {
      int rb = m0 + wm * 64 + i * 16 + (lane >> 4) * 4;
#pragma unroll
      for (int q = 0; q < 4; ++q) {
        float v = acc[i][j][q];
        s += v; ss += v * v;
        int row = rb + q;
        if (row < kN) out[(size_t)row * kC + col] = v + bv;
      }
    }
    s  += __shfl_xor(s, 16);  s  += __shfl_xor(s, 32);
    ss += __shfl_xor(ss, 16); ss += __shfl_xor(ss, 32);
    if (lane < 16) { atomicAdd(&cs[col], s); atomicAdd(&csq[col], ss); }
  }
}

// ---- BN normalize + PReLU + residual (stats are bias-free; shift mu by bias) ----
__global__ void k_final(float* __restrict__ h, const float* __restrict__ x,
                        const float* __restrict__ cs, const float* __restrict__ csq,
                        const float* __restrict__ bias,
                        const float* __restrict__ gamma, const float* __restrict__ beta,
                        const float* __restrict__ prelu) {
  int idx = (blockIdx.x * blockDim.x + threadIdx.x) * 4;
  if (idx >= kN * kC) return;
  int col = idx & 255;
  const float inv_n = 1.0f / (float)kN;
  float a = prelu[0];
  float4 hv = *(float4*)(h + idx);
  float4 xv = *(const float4*)(x + idx);
  float hr[4] = {hv.x, hv.y, hv.z, hv.w};
  float xr[4] = {xv.x, xv.y, xv.z, xv.w};
#pragma unroll
  for (int j = 0; j < 4; ++j) {
    int c = col + j;
    float mu_raw = cs[c] * inv_n;
    float var = csq[c] * inv_n - mu_raw * mu_raw;
    float mu  = mu_raw + bias[c];          // h was stored with bias added
    float k   = gamma[c] * rsqrtf(var + 1e-5f);
    float v   = (hr[j] - mu) * k + beta[c];
    v = v > 0.f ? v : a * v;
    hr[j] = v + xr[j];
  }
  *(float4*)(h + idx) = make_float4(hr[0], hr[1], hr[2], hr[3]);
}

extern "C" void kernel_launch(void* const* d_in, const int* in_sizes, int n_in,
                              void* d_out, int out_size, void* d_ws, size_t ws_size,
                              hipStream_t stream) {
  const float* x     = (const float*)d_in[0];
  const int*   ei    = (const int*)d_in[1];     // int64 in ref -> int32 from harness
  const float* ea    = (const float*)d_in[2];
  const float* W     = (const float*)d_in[3];
  const float* root  = (const float*)d_in[4];
  const float* bias  = (const float*)d_in[5];
  const float* gamma = (const float*)d_in[6];
  const float* beta  = (const float*)d_in[7];
  const float* prelu = (const float*)d_in[8];
  float* out = (float*)d_out;
  char* ws = (char*)d_ws;

  size_t o = 0;
  auto alloc = [&](size_t sz) { size_t r = o; o += (sz + 255) & ~(size_t)255; return r; };
  size_t a_o    = alloc((size_t)kMP * kK * 2);       // 230.6 MB
  size_t wbf_o  = alloc((size_t)kC * kK * 2);        // 1.2 MB
  size_t cnt_o  = alloc((size_t)kR * kN * 4);        // 1.6 MB
  size_t cs_o   = alloc(256 * 4);
  size_t csq_o  = alloc(256 * 4);
  size_t csr_o  = alloc(256);                        // global cursor (1 int)
  size_t zend   = o;                                 // end of must-zero region
  size_t off_o  = alloc((size_t)kN * 4);
  size_t cur_o  = alloc((size_t)kR * kN * 4);
  size_t eb_o   = alloc((size_t)kE * 2);             // u16 src records
  if (o > ws_size) {
    fprintf(stderr, "[RGCN kernel] ws too small: need %zu have %zu\n", o, ws_size);
    return;
  }

  unsigned short* A    = (unsigned short*)(ws + a_o);
  unsigned short* wbfT = (unsigned short*)(ws + wbf_o);
  int*   cnt    = (int*)(ws + cnt_o);
  float* cs     = (float*)(ws + cs_o);
  float* csq    = (float*)(ws + csq_o);
  int*   cursor = (int*)(ws + csr_o);
  int*   offp   = (int*)(ws + off_o);
  int*   cur    = (int*)(ws + cur_o);
  unsigned short* ebuf = (unsigned short*)(ws + eb_o);

  hipMemsetAsync(ws + cnt_o, 0, zend - cnt_o, stream);                       // cnt/cs/csq/cursor
  hipMemsetAsync(ws + a_o + (size_t)kN * kK * 2, 0,
                 (size_t)(kMP - kN) * kK * 2, stream);                       // A pad rows
  k_count<<<(kE + 255) / 256, 256, 0, stream>>>(ei, ea, cnt);
  k_convert_x<<<(kN * kC / 4) / 256, 256, 0, stream>>>(x, A);
  k_convert_w<<<(kC * kK + 255) / 256, 256, 0, stream>>>(W, root, wbfT);
  k_grp<<<(kN + 255) / 256, 256, 0, stream>>>(cnt, cursor, offp, cur);
  k_fill<<<(kE + 255) / 256, 256, 0, stream>>>(ei, ea, cur, ebuf);
  k_agg<<<(kN + 3) / 4, 256, 0, stream>>>(ebuf, offp, cnt, A);
  k_gemm<<<kWG, 512, 0, stream>>>(A, wbfT, out, bias, cs, csq);
  k_final<<<(kN * kC / 4) / 256, 256, 0, stream>>>(out, x, cs, csq, bias, gamma, beta, prelu);
}